// Round 2
// baseline (40777.756 us; speedup 1.0000x reference)
//
#include <hip/hip_runtime.h>

#define Bv 128
#define Tv 256
#define Vv 512
#define Hv 1024
#define FH 4096   // 4*H
#define TD 255    // T-1 decoder steps

typedef unsigned short ushort_t;
typedef __attribute__((ext_vector_type(8))) short bf16x8;
typedef __attribute__((ext_vector_type(4))) float f32x4;

__device__ __forceinline__ ushort_t f2bf(float f) {
    unsigned u = __float_as_uint(f);
    unsigned r = (u + 0x7fffu + ((u >> 16) & 1u)) >> 16;
    return (ushort_t)r;
}
__device__ __forceinline__ float bf2f(ushort_t h) {
    return __uint_as_float(((unsigned)h) << 16);
}
__device__ __forceinline__ float sigm(float x) {
    return 1.0f / (1.0f + expf(-x));
}

// ---------------------------------------------------------------------------
// Split W [K][N] fp32 into transposed hi/lo bf16 [N][K]
// ---------------------------------------------------------------------------
__global__ __launch_bounds__(256) void wsplit_t(
    const float* __restrict__ W, int K, int N,
    ushort_t* __restrict__ hiT, ushort_t* __restrict__ loT)
{
    __shared__ float ts[32][65];
    const int n0 = blockIdx.x * 64, k0 = blockIdx.y * 32;
    const int tid = threadIdx.x;
#pragma unroll
    for (int i = 0; i < 8; i++) {
        int f = tid + i * 256;
        int k = f >> 6, nn = f & 63;
        ts[k][nn] = W[(size_t)(k0 + k) * N + n0 + nn];
    }
    __syncthreads();
#pragma unroll
    for (int i = 0; i < 8; i++) {
        int f = tid + i * 256;
        int nn = f >> 5, k = f & 31;
        float v = ts[k][nn];
        ushort_t h = f2bf(v);
        ushort_t l = f2bf(v - bf2f(h));
        size_t o = (size_t)(n0 + nn) * K + k0 + k;
        hiT[o] = h;
        loT[o] = l;
    }
}

// ---------------------------------------------------------------------------
// One-hot [rows][512] -> token index. One wave per row.
// ---------------------------------------------------------------------------
__global__ __launch_bounds__(256) void extract_tokens(
    const float* __restrict__ x, int* __restrict__ tok)
{
    int row = blockIdx.x * 4 + (threadIdx.x >> 6);
    int lane = threadIdx.x & 63;
    const float* p = x + (size_t)row * Vv;
    int found = -1;
#pragma unroll
    for (int i = 0; i < 8; i++)
        if (p[lane + i * 64] > 0.5f) found = lane + i * 64;
#pragma unroll
    for (int off = 32; off > 0; off >>= 1) {
        int o = __shfl_down(found, off);
        found = found > o ? found : o;
    }
    if (lane == 0) tok[row] = found;
}

// ---------------------------------------------------------------------------
__global__ void find_eos(const int* __restrict__ tok, int* __restrict__ idx)
{
    int b = threadIdx.x;
    int first = Tv - 1;
    for (int t = Tv - 1; t >= 0; t--)
        if (tok[b * Tv + t] == 1) first = t;
    idx[b] = first;
}

// ---------------------------------------------------------------------------
// Two-level epoch barrier over 256 blocks (no cooperative launch).
// bar[0]      : epoch flag (monotonic)
// bar[64]     : master counter (monotonic)
// bar[128+g*64]: sub-counter for group g = blockIdx&7 (32 blocks each)
// All counters monotonic -> no resets, no reuse races.
// ---------------------------------------------------------------------------
__device__ __forceinline__ void gbar(int* bar, int e)
{
    // publish this block's global writes (per-wave waitcnt + L2 writeback)
    __builtin_amdgcn_fence(__ATOMIC_RELEASE, "agent");
    __syncthreads();
    if (threadIdx.x == 0) {
        int g = blockIdx.x & 7;
        int old = __hip_atomic_fetch_add(&bar[128 + g * 64], 1,
                                         __ATOMIC_ACQ_REL, __HIP_MEMORY_SCOPE_AGENT);
        if (old == e * 32 + 31) {               // last of this group's 32
            int m = __hip_atomic_fetch_add(&bar[64], 1,
                                           __ATOMIC_ACQ_REL, __HIP_MEMORY_SCOPE_AGENT);
            if (m == e * 8 + 7) {               // last group
                __hip_atomic_store(&bar[0], e + 1,
                                   __ATOMIC_RELEASE, __HIP_MEMORY_SCOPE_AGENT);
            }
        }
        while (__hip_atomic_load(&bar[0], __ATOMIC_RELAXED,
                                 __HIP_MEMORY_SCOPE_AGENT) < e + 1)
            __builtin_amdgcn_s_sleep(1);
    }
    __syncthreads();
    // invalidate stale cached lines before reading other blocks' data
    __builtin_amdgcn_fence(__ATOMIC_ACQUIRE, "agent");
}

// ---------------------------------------------------------------------------
// PERSISTENT fused LSTM: 256 blocks (1/CU), plain launch + custom barrier.
// Partition: 64 col-groups (16 j x 4 gates = 64 z-cols) x 4 K-groups (256 k).
// Weights LDS-resident per phase (64 KB); c-state in registers.
// Per step: [prefetch tok+Wi] MFMA(z-partials) -> bar -> epilogue -> bar.
// ---------------------------------------------------------------------------
struct PArgs {
    const ushort_t *eWhiT, *eWloT, *dWhiT, *dWloT;   // [4096][1024] split
    const float *eWi, *dWi, *eb, *db;
    const int *etok, *dtok, *eidx;
    const ushort_t *hz_hi, *hz_lo;                   // zeroed initial h
    ushort_t *hb0_hi, *hb0_lo, *hb1_hi, *hb1_lo;     // ping-pong h
    ushort_t *hsv_hi, *hsv_lo;                       // encoder state @ eos
    ushort_t *hd_hi, *hd_lo;                         // decoder h history
    float* z_p;                                      // [4 kg][64 cg][128 b][64 c]
    int* bar;
};

__global__ __launch_bounds__(256) void lstm_persist(PArgs P)
{
    __shared__ ushort_t wlds[2][32][64][8];   // [hi/lo][kchunk][c][8] = 65536 B

    const int tid  = threadIdx.x;
    const int wave = tid >> 6, lane = tid & 63;
    const int n = lane & 15, quad = lane >> 4;
    const int wm = wave & 1, wn = wave >> 1;
    const int blk = blockIdx.x;
    const int cgi = blk & 63, kg = blk >> 6;
    const int j0 = cgi * 16;
    const int k0 = kg * 256;

    // ---- one-time (per phase) LDS weight fill: block's 64 z-cols x 256 k ----
    auto fill_w = [&](const ushort_t* hiT, const ushort_t* loT) {
#pragma unroll
        for (int i = 0; i < 16; i++) {
            int id = tid + i * 256;              // 0..4095 16B chunks
            int half = id >> 11, rem = id & 2047;
            int kch = rem & 31, c = rem >> 5;    // c: local z-col, g=c>>4, j'=c&15
            const ushort_t* src = half ? loT : hiT;
            bf16x8 v = *(const bf16x8*)(src +
                (size_t)((c >> 4) * Hv + j0 + (c & 15)) * Hv + k0 + kch * 8);
            *(bf16x8*)(&wlds[half][kch][c][0]) = v;
        }
    };

    // ---- per-step partial GEMM: z_p[kg] = h[128 x kslice] @ W[kslice x 64] ----
    auto mfma_phase = [&](const ushort_t* hih, const ushort_t* hil) {
        const f32x4 vzero = {0.f, 0.f, 0.f, 0.f};
        f32x4 acc[4][2];
#pragma unroll
        for (int mi = 0; mi < 4; mi++) { acc[mi][0] = vzero; acc[mi][1] = vzero; }
        const int cA = wn * 32 + n;
        const size_t abase = (size_t)(wm * 64 + n) * Hv + k0 + quad * 8;
#pragma unroll 2
        for (int kc = 0; kc < 256; kc += 32) {
            int kq = (kc >> 3) + quad;
            bf16x8 b0h = *(const bf16x8*)(&wlds[0][kq][cA][0]);
            bf16x8 b1h = *(const bf16x8*)(&wlds[0][kq][cA + 16][0]);
            bf16x8 b0l = *(const bf16x8*)(&wlds[1][kq][cA][0]);
            bf16x8 b1l = *(const bf16x8*)(&wlds[1][kq][cA + 16][0]);
#pragma unroll
            for (int mi = 0; mi < 4; mi++) {
                bf16x8 ah = *(const bf16x8*)(hih + abase + (size_t)mi * 16 * Hv + kc);
                bf16x8 al = *(const bf16x8*)(hil + abase + (size_t)mi * 16 * Hv + kc);
                acc[mi][0] = __builtin_amdgcn_mfma_f32_16x16x32_bf16(ah, b0h, acc[mi][0], 0, 0, 0);
                acc[mi][1] = __builtin_amdgcn_mfma_f32_16x16x32_bf16(ah, b1h, acc[mi][1], 0, 0, 0);
                acc[mi][0] = __builtin_amdgcn_mfma_f32_16x16x32_bf16(al, b0h, acc[mi][0], 0, 0, 0);
                acc[mi][1] = __builtin_amdgcn_mfma_f32_16x16x32_bf16(al, b1h, acc[mi][1], 0, 0, 0);
                acc[mi][0] = __builtin_amdgcn_mfma_f32_16x16x32_bf16(ah, b0l, acc[mi][0], 0, 0, 0);
                acc[mi][1] = __builtin_amdgcn_mfma_f32_16x16x32_bf16(ah, b1l, acc[mi][1], 0, 0, 0);
            }
        }
        // C/D layout: col = lane&15 (z-col), row = quad*4+r (batch)
#pragma unroll
        for (int mi = 0; mi < 4; mi++)
#pragma unroll
            for (int gs = 0; gs < 2; gs++) {
                int cloc = (2 * wn + gs) * 16 + n;
#pragma unroll
                for (int r = 0; r < 4; r++) {
                    int b = wm * 64 + mi * 16 + quad * 4 + r;
                    P.z_p[(((size_t)kg * 64 + cgi) * 128 + b) * 64 + cloc] = acc[mi][gs][r];
                }
            }
    };

    // ---- epilogue ownership: 2 (b,j) elements per thread, fixed for all t ----
    const int b_e0 = kg * 32 + (tid >> 4);
    const int b_e1 = b_e0 + 16;
    const int jp   = tid & 15;
    const int j    = j0 + jp;

    const float eb_0 = P.eb[j], eb_1 = P.eb[Hv + j], eb_2 = P.eb[2 * Hv + j], eb_3 = P.eb[3 * Hv + j];
    const float db_0 = P.db[j], db_1 = P.db[Hv + j], db_2 = P.db[2 * Hv + j], db_3 = P.db[3 * Hv + j];
    const int eidx0 = P.eidx[b_e0], eidx1 = P.eidx[b_e1];
    float c0 = 0.f, c1 = 0.f, csv0 = 0.f, csv1 = 0.f;

    // epilogue: z-partial reduce + gates; Wi contribution preloaded (w0..w3)
    auto do_elem = [&](int b, float w0, float w1, float w2, float w3,
                       float bz0, float bz1, float bz2, float bz3,
                       float& cc, ushort_t* oh, ushort_t* ol,
                       ushort_t* xh, ushort_t* xl, bool xen,
                       float* csv) {
        float z0 = bz0 + w0, z1 = bz1 + w1, z2 = bz2 + w2, z3 = bz3 + w3;
#pragma unroll
        for (int q = 0; q < 4; q++) {
            const float* zq = P.z_p + (((size_t)q * 64 + cgi) * 128 + b) * 64 + jp;
            z0 += zq[0]; z1 += zq[16]; z2 += zq[32]; z3 += zq[48];
        }
        float si = sigm(z0), sf = sigm(z1), so = sigm(z3);
        float gg = tanhf(z2);
        float cn = sf * cc + si * gg; cc = cn;
        float hn = so * tanhf(cn);
        ushort_t hh = f2bf(hn);
        ushort_t hl = f2bf(hn - bf2f(hh));
        size_t off = (size_t)b * Hv + j;
        oh[off] = hh; ol[off] = hl;
        if (xen) {
            xh[off] = hh; xl[off] = hl;
            if (csv) *csv = cn;
        }
    };

    int ep = 0;

    // ================= encoder =================
    fill_w(P.eWhiT, P.eWloT);
    __syncthreads();
    const ushort_t* ih = P.hz_hi;
    const ushort_t* il = P.hz_lo;
    for (int t = 0; t < Tv; t++) {
        // prefetch tok + Wi rows (latency hides under MFMA phase)
        int tk0 = P.etok[b_e0 * Tv + t], tk1 = P.etok[b_e1 * Tv + t];
        const float* wr0 = P.eWi + (size_t)tk0 * FH + j;
        const float* wr1 = P.eWi + (size_t)tk1 * FH + j;
        float a00 = wr0[0], a01 = wr0[Hv], a02 = wr0[2 * Hv], a03 = wr0[3 * Hv];
        float a10 = wr1[0], a11 = wr1[Hv], a12 = wr1[2 * Hv], a13 = wr1[3 * Hv];
        mfma_phase(ih, il);
        gbar(P.bar, ep); ep++;
        ushort_t* oh = (t & 1) ? P.hb1_hi : P.hb0_hi;
        ushort_t* ol = (t & 1) ? P.hb1_lo : P.hb0_lo;
        do_elem(b_e0, a00, a01, a02, a03, eb_0, eb_1, eb_2, eb_3,
                c0, oh, ol, P.hsv_hi, P.hsv_lo, t == eidx0, &csv0);
        do_elem(b_e1, a10, a11, a12, a13, eb_0, eb_1, eb_2, eb_3,
                c1, oh, ol, P.hsv_hi, P.hsv_lo, t == eidx1, &csv1);
        gbar(P.bar, ep); ep++;
        ih = oh; il = ol;
    }

    // ================= decoder =================
    fill_w(P.dWhiT, P.dWloT);   // block-local; all blocks past the last barrier
    __syncthreads();
    c0 = csv0; c1 = csv1;
    ih = P.hsv_hi; il = P.hsv_lo;
    for (int t = 0; t < TD; t++) {
        int tk0 = P.dtok[b_e0 * Tv + t], tk1 = P.dtok[b_e1 * Tv + t];
        const float* wr0 = P.dWi + (size_t)tk0 * FH + j;
        const float* wr1 = P.dWi + (size_t)tk1 * FH + j;
        float a00 = wr0[0], a01 = wr0[Hv], a02 = wr0[2 * Hv], a03 = wr0[3 * Hv];
        float a10 = wr1[0], a11 = wr1[Hv], a12 = wr1[2 * Hv], a13 = wr1[3 * Hv];
        mfma_phase(ih, il);
        gbar(P.bar, ep); ep++;
        ushort_t* oh = (t & 1) ? P.hb1_hi : P.hb0_hi;
        ushort_t* ol = (t & 1) ? P.hb1_lo : P.hb0_lo;
        ushort_t* xh = P.hd_hi + (size_t)t * (Bv * Hv);
        ushort_t* xl = P.hd_lo + (size_t)t * (Bv * Hv);
        do_elem(b_e0, a00, a01, a02, a03, db_0, db_1, db_2, db_3,
                c0, oh, ol, xh, xl, true, nullptr);
        do_elem(b_e1, a10, a11, a12, a13, db_0, db_1, db_2, db_3,
                c1, oh, ol, xh, xl, true, nullptr);
        gbar(P.bar, ep); ep++;
        ih = oh; il = ol;
    }
}

// ---------------------------------------------------------------------------
// logits = hd @ dense_W + b : [32640,1024] x [1024,512], bf16x3 MFMA.
// ---------------------------------------------------------------------------
__global__ __launch_bounds__(256) void dense_mfma(
    const ushort_t* __restrict__ Ahi, const ushort_t* __restrict__ Alo, // [32640][1024]
    const ushort_t* __restrict__ WhiT, const ushort_t* __restrict__ WloT, // [512][1024]
    const float* __restrict__ bias, float* __restrict__ out)
{
    const int tid = threadIdx.x;
    const int wave = tid >> 6, lane = tid & 63;
    const int wm = wave & 1, wn = wave >> 1;
    const int n = lane & 15, quad = lane >> 4;
    const int m0 = blockIdx.y * 32 + wm * 16;
    const int c0 = blockIdx.x * 64 + wn * 32;

    const size_t arow = (size_t)(m0 + n) * Hv + quad * 8;
    const size_t g0 = (size_t)(c0 + 0 + n) * Hv + quad * 8;
    const size_t g1 = (size_t)(c0 + 16 + n) * Hv + quad * 8;

    f32x4 acc0 = {0.f, 0.f, 0.f, 0.f}, acc1 = {0.f, 0.f, 0.f, 0.f};

#pragma unroll 2
    for (int kc = 0; kc < Hv; kc += 32) {
        bf16x8 ahi = *(const bf16x8*)(Ahi + arow + kc);
        bf16x8 alo = *(const bf16x8*)(Alo + arow + kc);
        bf16x8 b0h = *(const bf16x8*)(WhiT + g0 + kc);
        bf16x8 b0l = *(const bf16x8*)(WloT + g0 + kc);
        bf16x8 b1h = *(const bf16x8*)(WhiT + g1 + kc);
        bf16x8 b1l = *(const bf16x8*)(WloT + g1 + kc);
        acc0 = __builtin_amdgcn_mfma_f32_16x16x32_bf16(ahi, b0h, acc0, 0, 0, 0);
        acc1 = __builtin_amdgcn_mfma_f32_16x16x32_bf16(ahi, b1h, acc1, 0, 0, 0);
        acc0 = __builtin_amdgcn_mfma_f32_16x16x32_bf16(alo, b0h, acc0, 0, 0, 0);
        acc1 = __builtin_amdgcn_mfma_f32_16x16x32_bf16(alo, b1h, acc1, 0, 0, 0);
        acc0 = __builtin_amdgcn_mfma_f32_16x16x32_bf16(ahi, b0l, acc0, 0, 0, 0);
        acc1 = __builtin_amdgcn_mfma_f32_16x16x32_bf16(ahi, b1l, acc1, 0, 0, 0);
    }

#pragma unroll
    for (int r = 0; r < 4; r++) {
        int row = m0 + quad * 4 + r;
        int tt = row >> 7, bb = row & 127;
        size_t o = ((size_t)bb * TD + tt) * Vv;
        int col0 = c0 + n, col1 = c0 + 16 + n;
        out[o + col0] = acc0[r] + bias[col0];
        out[o + col1] = acc1[r] + bias[col1];
    }
}

// ---------------------------------------------------------------------------
extern "C" void kernel_launch(void* const* d_in, const int* in_sizes, int n_in,
                              void* d_out, int out_size, void* d_ws, size_t ws_size,
                              hipStream_t stream)
{
    const float* enc_in  = (const float*)d_in[0];
    const float* dec_in  = (const float*)d_in[1];
    const float* enc_Wi  = (const float*)d_in[2];
    const float* enc_Wh  = (const float*)d_in[3];
    const float* enc_b   = (const float*)d_in[4];
    const float* dec_Wi  = (const float*)d_in[5];
    const float* dec_Wh  = (const float*)d_in[6];
    const float* dec_b   = (const float*)d_in[7];
    const float* dense_W = (const float*)d_in[8];
    const float* dense_b = (const float*)d_in[9];
    float* out = (float*)d_out;

    char* wp = (char*)d_ws;
    auto take = [&](size_t bytes) -> char* {
        char* p = wp;
        wp += (bytes + 255) & ~(size_t)255;
        return p;
    };

    ushort_t* hd_hi = (ushort_t*)take((size_t)TD * Bv * Hv * 2);
    ushort_t* hd_lo = (ushort_t*)take((size_t)TD * Bv * Hv * 2);
    ushort_t* eWhi  = (ushort_t*)take((size_t)FH * Hv * 2);
    ushort_t* eWlo  = (ushort_t*)take((size_t)FH * Hv * 2);
    ushort_t* dWhi  = (ushort_t*)take((size_t)FH * Hv * 2);
    ushort_t* dWlo  = (ushort_t*)take((size_t)FH * Hv * 2);
    ushort_t* nWhi  = (ushort_t*)take((size_t)Vv * Hv * 2);
    ushort_t* nWlo  = (ushort_t*)take((size_t)Vv * Hv * 2);
    ushort_t* hzhi  = (ushort_t*)take((size_t)Bv * Hv * 2);
    ushort_t* hzlo  = (ushort_t*)take((size_t)Bv * Hv * 2);
    ushort_t* hb0h  = (ushort_t*)take((size_t)Bv * Hv * 2);
    ushort_t* hb0l  = (ushort_t*)take((size_t)Bv * Hv * 2);
    ushort_t* hb1h  = (ushort_t*)take((size_t)Bv * Hv * 2);
    ushort_t* hb1l  = (ushort_t*)take((size_t)Bv * Hv * 2);
    ushort_t* hshi  = (ushort_t*)take((size_t)Bv * Hv * 2);
    ushort_t* hslo  = (ushort_t*)take((size_t)Bv * Hv * 2);
    float*    z_p   = (float*)take((size_t)4 * Bv * FH * 4);
    int*      etok  = (int*)take((size_t)Bv * Tv * 4);
    int*      dtok  = (int*)take((size_t)Bv * Tv * 4);
    int*      eidx  = (int*)take((size_t)Bv * 4);
    int*      bar   = (int*)take(4096);

    // --- preprocess: weight split+transpose, token extraction, lengths -----
    wsplit_t<<<dim3(FH / 64, Hv / 32), 256, 0, stream>>>(enc_Wh, Hv, FH, eWhi, eWlo);
    wsplit_t<<<dim3(FH / 64, Hv / 32), 256, 0, stream>>>(dec_Wh, Hv, FH, dWhi, dWlo);
    wsplit_t<<<dim3(Vv / 64, Hv / 32), 256, 0, stream>>>(dense_W, Hv, Vv, nWhi, nWlo);
    extract_tokens<<<Bv * Tv / 4, 256, 0, stream>>>(enc_in, etok);
    extract_tokens<<<Bv * Tv / 4, 256, 0, stream>>>(dec_in, dtok);
    find_eos<<<1, Bv, 0, stream>>>(etok, eidx);

    hipMemsetAsync(hzhi, 0, (size_t)Bv * Hv * 2, stream);
    hipMemsetAsync(hzlo, 0, (size_t)Bv * Hv * 2, stream);
    hipMemsetAsync(bar, 0, 4096, stream);

    // --- persistent fused LSTM (plain launch + custom epoch barrier) --------
    PArgs pa;
    pa.eWhiT = eWhi; pa.eWloT = eWlo; pa.dWhiT = dWhi; pa.dWloT = dWlo;
    pa.eWi = enc_Wi; pa.dWi = dec_Wi; pa.eb = enc_b; pa.db = dec_b;
    pa.etok = etok; pa.dtok = dtok; pa.eidx = eidx;
    pa.hz_hi = hzhi; pa.hz_lo = hzlo;
    pa.hb0_hi = hb0h; pa.hb0_lo = hb0l; pa.hb1_hi = hb1h; pa.hb1_lo = hb1l;
    pa.hsv_hi = hshi; pa.hsv_lo = hslo;
    pa.hd_hi = hd_hi; pa.hd_lo = hd_lo;
    pa.z_p = z_p;
    pa.bar = bar;

    lstm_persist<<<dim3(256), dim3(256), 0, stream>>>(pa);

    // --- dense head ---------------------------------------------------------
    dense_mfma<<<dim3(Vv / 64, (TD * Bv) / 32), 256, 0, stream>>>(
        hd_hi, hd_lo, nWhi, nWlo, dense_b, out);
}

// Round 4
// 13527.264 us; speedup vs baseline: 3.0145x; 3.0145x over previous
//
#include <hip/hip_runtime.h>

#define Bv 128
#define Tv 256
#define Vv 512
#define Hv 1024
#define FH 4096   // 4*H
#define TD 255    // T-1 decoder steps

typedef unsigned short ushort_t;
typedef __attribute__((ext_vector_type(8))) short bf16x8;
typedef __attribute__((ext_vector_type(4))) float f32x4;

__device__ __forceinline__ ushort_t f2bf(float f) {
    unsigned u = __float_as_uint(f);
    unsigned r = (u + 0x7fffu + ((u >> 16) & 1u)) >> 16;
    return (ushort_t)r;
}
__device__ __forceinline__ float bf2f(ushort_t h) {
    return __uint_as_float(((unsigned)h) << 16);
}
__device__ __forceinline__ float sigm(float x) {
    return 1.0f / (1.0f + expf(-x));
}

// ---------------------------------------------------------------------------
// Split W [K][N] fp32 into transposed hi/lo bf16 [N][K]
// grid (N/64, K/32), 256 threads
// ---------------------------------------------------------------------------
__global__ __launch_bounds__(256) void wsplit_t(
    const float* __restrict__ W, int K, int N,
    ushort_t* __restrict__ hiT, ushort_t* __restrict__ loT)
{
    __shared__ float ts[32][65];
    const int n0 = blockIdx.x * 64, k0 = blockIdx.y * 32;
    const int tid = threadIdx.x;
#pragma unroll
    for (int i = 0; i < 8; i++) {
        int f = tid + i * 256;
        int k = f >> 6, nn = f & 63;
        ts[k][nn] = W[(size_t)(k0 + k) * N + n0 + nn];
    }
    __syncthreads();
#pragma unroll
    for (int i = 0; i < 8; i++) {
        int f = tid + i * 256;
        int nn = f >> 5, k = f & 31;
        float v = ts[k][nn];
        ushort_t h = f2bf(v);
        ushort_t l = f2bf(v - bf2f(h));
        size_t o = (size_t)(n0 + nn) * K + k0 + k;
        hiT[o] = h;
        loT[o] = l;
    }
}

// ---------------------------------------------------------------------------
// One-hot [rows][512] -> token index. One wave per row.
// ---------------------------------------------------------------------------
__global__ __launch_bounds__(256) void extract_tokens(
    const float* __restrict__ x, int* __restrict__ tok)
{
    int row = blockIdx.x * 4 + (threadIdx.x >> 6);
    int lane = threadIdx.x & 63;
    const float* p = x + (size_t)row * Vv;
    int found = -1;
#pragma unroll
    for (int i = 0; i < 8; i++)
        if (p[lane + i * 64] > 0.5f) found = lane + i * 64;
#pragma unroll
    for (int off = 32; off > 0; off >>= 1) {
        int o = __shfl_down(found, off);
        found = found > o ? found : o;
    }
    if (lane == 0) tok[row] = found;
}

// ---------------------------------------------------------------------------
// First position where enc token == EOS(1); idx = eos_pos (or T-1 if absent)
// ---------------------------------------------------------------------------
__global__ void find_eos(const int* __restrict__ tok, int* __restrict__ idx)
{
    int b = threadIdx.x;
    int first = Tv - 1;
    for (int t = Tv - 1; t >= 0; t--)
        if (tok[b * Tv + t] == 1) first = t;
    idx[b] = first;
}

// ---------------------------------------------------------------------------
// One LSTM step. grid (64 j-tiles, 4 b-tiles), 1024 threads = 16 waves.
// Waves: wk = wave>>2 (K-quarter, 256 k each), wm = wave&1 (batch 16-tile),
//        wn = (wave>>1)&1 (col 32-tile). Partial z summed across wk in LDS.
// 4 waves/SIMD (vs baseline 1) hides L2/LLC latency; weight traffic unchanged
// (and b-duplicate blocks land on the same XCD: ids differ by 64 = 0 mod 8,
//  so each XCD caches only its 8 j-columns of weights = 2 MB < 4 MB L2).
// Epilogue inputs (tok, Wi row, bias, c) prefetched before MFMA loop.
// ---------------------------------------------------------------------------
__global__ __launch_bounds__(1024, 4) void lstm_step(
    const ushort_t* __restrict__ WhiT, const ushort_t* __restrict__ WloT, // [4096][1024]
    const float* __restrict__ Wi,      // [512][4096] fp32 (exact gather)
    const float* __restrict__ bias,    // [4096]
    const int* __restrict__ tok, int t,
    const ushort_t* __restrict__ hin_hi, const ushort_t* __restrict__ hin_lo, // [B][H]
    ushort_t* __restrict__ hout_hi, ushort_t* __restrict__ hout_lo,
    float* __restrict__ c_state,       // [B][H] in/out (exact fp32)
    ushort_t* __restrict__ hex_hi, ushort_t* __restrict__ hex_lo,   // nullable: hd slice
    const int* __restrict__ save_idx,                               // nullable: encoder save
    float* __restrict__ c_save, ushort_t* __restrict__ hs_hi, ushort_t* __restrict__ hs_lo)
{
    __shared__ float z_s[4][32][68];
    const int tid = threadIdx.x;
    const int wave = tid >> 6, lane = tid & 63;
    const int wk = wave >> 2;
    const int wm = wave & 1, wn = (wave >> 1) & 1;
    const int n = lane & 15, quad = lane >> 4;
    const int j0 = blockIdx.x * 16;
    const int b0 = blockIdx.y * 32;
    const int k0 = wk * 256;

    // ---- epilogue prefetch: one (b, j) element per thread for tid < 512 ----
    const bool act = tid < 512;
    const int bl = tid >> 4, jl = tid & 15;   // bl 0..31 (valid when act)
    const int b_e = b0 + bl, col = j0 + jl;
    float w0 = 0.f, w1 = 0.f, w2 = 0.f, w3 = 0.f;
    float bz0 = 0.f, bz1 = 0.f, bz2 = 0.f, bz3 = 0.f;
    float c_old = 0.f;
    int sidx = -1;
    size_t off = 0;
    if (act) {
        int tk = tok[b_e * Tv + t];
        const float* wr = Wi + (size_t)tk * FH + col;
        w0 = wr[0]; w1 = wr[Hv]; w2 = wr[2 * Hv]; w3 = wr[3 * Hv];
        bz0 = bias[col];          bz1 = bias[Hv + col];
        bz2 = bias[2 * Hv + col]; bz3 = bias[3 * Hv + col];
        off = (size_t)b_e * Hv + col;
        c_old = c_state[off];
        if (save_idx) sidx = save_idx[b_e];
    }

    // A fragment source: h row (batch), 8 consecutive k per lane
    const size_t arow = (size_t)(b0 + wm * 16 + n) * Hv + k0 + quad * 8;
    // B fragment source: transposed weight rows for the two gate-subtiles
    const size_t g0 = (size_t)((2 * wn + 0) * Hv + j0 + n) * Hv + k0 + quad * 8;
    const size_t g1 = (size_t)((2 * wn + 1) * Hv + j0 + n) * Hv + k0 + quad * 8;

    f32x4 acc0 = {0.f, 0.f, 0.f, 0.f}, acc1 = {0.f, 0.f, 0.f, 0.f};

#pragma unroll 2
    for (int kc = 0; kc < 256; kc += 32) {
        bf16x8 ahi = *(const bf16x8*)(hin_hi + arow + kc);
        bf16x8 alo = *(const bf16x8*)(hin_lo + arow + kc);
        bf16x8 b0h = *(const bf16x8*)(WhiT + g0 + kc);
        bf16x8 b0l = *(const bf16x8*)(WloT + g0 + kc);
        bf16x8 b1h = *(const bf16x8*)(WhiT + g1 + kc);
        bf16x8 b1l = *(const bf16x8*)(WloT + g1 + kc);
        acc0 = __builtin_amdgcn_mfma_f32_16x16x32_bf16(ahi, b0h, acc0, 0, 0, 0);
        acc1 = __builtin_amdgcn_mfma_f32_16x16x32_bf16(ahi, b1h, acc1, 0, 0, 0);
        acc0 = __builtin_amdgcn_mfma_f32_16x16x32_bf16(alo, b0h, acc0, 0, 0, 0);
        acc1 = __builtin_amdgcn_mfma_f32_16x16x32_bf16(alo, b1h, acc1, 0, 0, 0);
        acc0 = __builtin_amdgcn_mfma_f32_16x16x32_bf16(ahi, b0l, acc0, 0, 0, 0);
        acc1 = __builtin_amdgcn_mfma_f32_16x16x32_bf16(ahi, b1l, acc1, 0, 0, 0);
    }

    // C/D layout: col = lane&15, row = quad*4 + r  -> scatter to LDS
    const int row0 = wm * 16 + quad * 4;
    const int cb0 = (2 * wn + 0) * 16 + n;
    const int cb1 = cb0 + 16;
#pragma unroll
    for (int r = 0; r < 4; r++) {
        z_s[wk][row0 + r][cb0] = acc0[r];
        z_s[wk][row0 + r][cb1] = acc1[r];
    }
    __syncthreads();

    if (act) {
        float z0 = bz0 + w0, z1 = bz1 + w1, z2 = bz2 + w2, z3 = bz3 + w3;
#pragma unroll
        for (int q = 0; q < 4; q++) {
            z0 += z_s[q][bl][jl];
            z1 += z_s[q][bl][16 + jl];
            z2 += z_s[q][bl][32 + jl];
            z3 += z_s[q][bl][48 + jl];
        }
        float si = sigm(z0), sf = sigm(z1), so = sigm(z3);
        float gg = tanhf(z2);
        float cn = sf * c_old + si * gg;
        float hn = so * tanhf(cn);
        c_state[off] = cn;
        ushort_t hh = f2bf(hn);
        ushort_t hl = f2bf(hn - bf2f(hh));
        hout_hi[off] = hh;
        hout_lo[off] = hl;
        if (hex_hi) { hex_hi[off] = hh; hex_lo[off] = hl; }
        if (save_idx) {
            if (t == sidx) { c_save[off] = cn; hs_hi[off] = hh; hs_lo[off] = hl; }
        }
    }
}

// ---------------------------------------------------------------------------
// logits = hd @ dense_W + b : [32640,1024] x [1024,512], bf16x3 MFMA.
// grid (8, 1020), 256 threads; block 32 m x 64 n; wave 16 m x 32 n.
// row r = t*B + b ; out index = (b*TD + t)*V + col
// ---------------------------------------------------------------------------
__global__ __launch_bounds__(256) void dense_mfma(
    const ushort_t* __restrict__ Ahi, const ushort_t* __restrict__ Alo, // [32640][1024]
    const ushort_t* __restrict__ WhiT, const ushort_t* __restrict__ WloT, // [512][1024]
    const float* __restrict__ bias, float* __restrict__ out)
{
    const int tid = threadIdx.x;
    const int wave = tid >> 6, lane = tid & 63;
    const int wm = wave & 1, wn = wave >> 1;
    const int n = lane & 15, quad = lane >> 4;
    const int m0 = blockIdx.y * 32 + wm * 16;
    const int c0 = blockIdx.x * 64 + wn * 32;

    const size_t arow = (size_t)(m0 + n) * Hv + quad * 8;
    const size_t g0 = (size_t)(c0 + 0 + n) * Hv + quad * 8;
    const size_t g1 = (size_t)(c0 + 16 + n) * Hv + quad * 8;

    f32x4 acc0 = {0.f, 0.f, 0.f, 0.f}, acc1 = {0.f, 0.f, 0.f, 0.f};

#pragma unroll 2
    for (int kc = 0; kc < Hv; kc += 32) {
        bf16x8 ahi = *(const bf16x8*)(Ahi + arow + kc);
        bf16x8 alo = *(const bf16x8*)(Alo + arow + kc);
        bf16x8 b0h = *(const bf16x8*)(WhiT + g0 + kc);
        bf16x8 b0l = *(const bf16x8*)(WloT + g0 + kc);
        bf16x8 b1h = *(const bf16x8*)(WhiT + g1 + kc);
        bf16x8 b1l = *(const bf16x8*)(WloT + g1 + kc);
        acc0 = __builtin_amdgcn_mfma_f32_16x16x32_bf16(ahi, b0h, acc0, 0, 0, 0);
        acc1 = __builtin_amdgcn_mfma_f32_16x16x32_bf16(ahi, b1h, acc1, 0, 0, 0);
        acc0 = __builtin_amdgcn_mfma_f32_16x16x32_bf16(alo, b0h, acc0, 0, 0, 0);
        acc1 = __builtin_amdgcn_mfma_f32_16x16x32_bf16(alo, b1h, acc1, 0, 0, 0);
        acc0 = __builtin_amdgcn_mfma_f32_16x16x32_bf16(ahi, b0l, acc0, 0, 0, 0);
        acc1 = __builtin_amdgcn_mfma_f32_16x16x32_bf16(ahi, b1l, acc1, 0, 0, 0);
    }

#pragma unroll
    for (int r = 0; r < 4; r++) {
        int row = m0 + quad * 4 + r;
        int tt = row >> 7, bb = row & 127;
        size_t o = ((size_t)bb * TD + tt) * Vv;
        int col0 = c0 + n, col1 = c0 + 16 + n;
        out[o + col0] = acc0[r] + bias[col0];
        out[o + col1] = acc1[r] + bias[col1];
    }
}

// ---------------------------------------------------------------------------
extern "C" void kernel_launch(void* const* d_in, const int* in_sizes, int n_in,
                              void* d_out, int out_size, void* d_ws, size_t ws_size,
                              hipStream_t stream)
{
    const float* enc_in  = (const float*)d_in[0];
    const float* dec_in  = (const float*)d_in[1];
    const float* enc_Wi  = (const float*)d_in[2];
    const float* enc_Wh  = (const float*)d_in[3];
    const float* enc_b   = (const float*)d_in[4];
    const float* dec_Wi  = (const float*)d_in[5];
    const float* dec_Wh  = (const float*)d_in[6];
    const float* dec_b   = (const float*)d_in[7];
    const float* dense_W = (const float*)d_in[8];
    const float* dense_b = (const float*)d_in[9];
    float* out = (float*)d_out;

    char* wp = (char*)d_ws;
    auto take = [&](size_t bytes) -> char* {
        char* p = wp;
        wp += (bytes + 255) & ~(size_t)255;
        return p;
    };

    ushort_t* hd_hi = (ushort_t*)take((size_t)TD * Bv * Hv * 2);
    ushort_t* hd_lo = (ushort_t*)take((size_t)TD * Bv * Hv * 2);
    ushort_t* eWhi  = (ushort_t*)take((size_t)FH * Hv * 2);
    ushort_t* eWlo  = (ushort_t*)take((size_t)FH * Hv * 2);
    ushort_t* dWhi  = (ushort_t*)take((size_t)FH * Hv * 2);
    ushort_t* dWlo  = (ushort_t*)take((size_t)FH * Hv * 2);
    ushort_t* nWhi  = (ushort_t*)take((size_t)Vv * Hv * 2);
    ushort_t* nWlo  = (ushort_t*)take((size_t)Vv * Hv * 2);
    ushort_t* hbh0  = (ushort_t*)take((size_t)Bv * Hv * 2);
    ushort_t* hbl0  = (ushort_t*)take((size_t)Bv * Hv * 2);
    ushort_t* hbh1  = (ushort_t*)take((size_t)Bv * Hv * 2);
    ushort_t* hbl1  = (ushort_t*)take((size_t)Bv * Hv * 2);
    ushort_t* hshi  = (ushort_t*)take((size_t)Bv * Hv * 2);
    ushort_t* hslo  = (ushort_t*)take((size_t)Bv * Hv * 2);
    float*    c_state = (float*)take((size_t)Bv * Hv * 4);
    float*    c_save  = (float*)take((size_t)Bv * Hv * 4);
    int*      etok  = (int*)take((size_t)Bv * Tv * 4);
    int*      dtok  = (int*)take((size_t)Bv * Tv * 4);
    int*      eidx  = (int*)take((size_t)Bv * 4);

    ushort_t* hbh[2] = {hbh0, hbh1};
    ushort_t* hbl[2] = {hbl0, hbl1};

    // --- preprocess: weight split+transpose, token extraction, lengths -----
    wsplit_t<<<dim3(FH / 64, Hv / 32), 256, 0, stream>>>(enc_Wh, Hv, FH, eWhi, eWlo);
    wsplit_t<<<dim3(FH / 64, Hv / 32), 256, 0, stream>>>(dec_Wh, Hv, FH, dWhi, dWlo);
    wsplit_t<<<dim3(Vv / 64, Hv / 32), 256, 0, stream>>>(dense_W, Hv, Vv, nWhi, nWlo);
    extract_tokens<<<Bv * Tv / 4, 256, 0, stream>>>(enc_in, etok);
    extract_tokens<<<Bv * Tv / 4, 256, 0, stream>>>(dec_in, dtok);
    find_eos<<<1, Bv, 0, stream>>>(etok, eidx);

    hipMemsetAsync(hbh0, 0, (size_t)Bv * Hv * 2, stream);
    hipMemsetAsync(hbl0, 0, (size_t)Bv * Hv * 2, stream);
    hipMemsetAsync(c_state, 0, (size_t)Bv * Hv * 4, stream);

    // --- encoder: 256 steps, save state at t == eos_idx[b] ------------------
    for (int t = 0; t < Tv; t++) {
        lstm_step<<<dim3(64, 4), 1024, 0, stream>>>(
            eWhi, eWlo, enc_Wi, enc_b, etok, t,
            hbh[t & 1], hbl[t & 1], hbh[(t + 1) & 1], hbl[(t + 1) & 1],
            c_state, nullptr, nullptr, eidx, c_save, hshi, hslo);
    }

    // --- phase switch: decoder initial state = saved encoder state ---------
    hipMemcpyAsync(c_state, c_save, (size_t)Bv * Hv * 4, hipMemcpyDeviceToDevice, stream);
    hipMemcpyAsync(hbh0, hshi, (size_t)Bv * Hv * 2, hipMemcpyDeviceToDevice, stream);
    hipMemcpyAsync(hbl0, hslo, (size_t)Bv * Hv * 2, hipMemcpyDeviceToDevice, stream);

    // --- decoder: 255 steps, store h (split) for dense GEMM -----------------
    for (int t = 0; t < TD; t++) {
        lstm_step<<<dim3(64, 4), 1024, 0, stream>>>(
            dWhi, dWlo, dec_Wi, dec_b, dtok, t,
            hbh[t & 1], hbl[t & 1], hbh[(t + 1) & 1], hbl[(t + 1) & 1],
            c_state, hd_hi + (size_t)t * Bv * Hv, hd_lo + (size_t)t * Bv * Hv,
            nullptr, nullptr, nullptr, nullptr);
    }

    // --- dense head ---------------------------------------------------------
    dense_mfma<<<dim3(Vv / 64, (TD * Bv) / 32), 256, 0, stream>>>(
        hd_hi, hd_lo, nWhi, nWlo, dense_b, out);
}